// Round 11
// baseline (175.329 us; speedup 1.0000x reference)
//
#include <hip/hip_runtime.h>

#define Bn 8
#define Nn 16384
#define Cn 256
#define NC 32                   // split-K chunks over N (gram); K=512 per ck

typedef __attribute__((ext_vector_type(4)))  float f32x4;
typedef __attribute__((ext_vector_type(16))) float f32x16;
typedef __attribute__((ext_vector_type(8)))  _Float16 f16x8;
typedef __attribute__((ext_vector_type(8)))  unsigned short u16x8;

static __device__ __forceinline__ unsigned short f2h(float f) {
    return __builtin_bit_cast(unsigned short, (_Float16)f);
}
static __device__ __forceinline__ f32x16 mfma16h(u16x8 a, u16x8 b, f32x16 c) {
    return __builtin_amdgcn_mfma_f32_32x32x16_f16(
        __builtin_bit_cast(f16x8, a), __builtin_bit_cast(f16x8, b), c, 0, 0, 0);
}

// ---------------- K1 (k_gram): G-partial row-half per block; atomics into L2-resident G ----
// 512 blocks (b=XCD, ck, half); 256 thr = 4 waves (col groups), acc[4][2] (wave 128x64).
// Stage BK=64 cols fp32->fp16 into [256 rows][128B] LDS (rotation swizzle, conflict-free),
// double-buffered; 16 loads/thread in flight across compute. Epilogue: atomicAdd into
// G[b] (256KB/batch, stays in the XCD's L2 -> ~no HBM traffic for G). Row sums -> sv atomics.
__global__ __launch_bounds__(256, 2) void k_gram(
    const float* __restrict__ x, float* __restrict__ G,
    float* __restrict__ sv) {
  const int b    = blockIdx.x & 7;           // 1 batch per XCD
  const int loc  = blockIdx.x >> 3;          // 0..63; halves adjacent in dispatch
  const int ck   = loc >> 1;
  const int half = loc & 1;

  __shared__ __align__(16) char smem[2][32768];   // [256 rows][128B] fp16

  const int t     = threadIdx.x;
  const int lane  = t & 63;
  const int w     = t >> 6;                  // col group (cols w*64..)
  const int ln    = lane & 31, kh = lane >> 5;
  const int rquad = t >> 4;                  // 0..15
  const int c4    = t & 15;                  // 16B column slot within 64-col stage

  const float* xb = x + (size_t)b * ((size_t)Cn * Nn) + (size_t)ck * 512;

  f32x16 acc[4][2];
#pragma unroll
  for (int m = 0; m < 4; ++m)
#pragma unroll
    for (int n = 0; n < 2; ++n)
#pragma unroll
      for (int i = 0; i < 16; ++i) acc[m][n][i] = 0.f;

  float srow[16];
#pragma unroll
  for (int p = 0; p < 16; ++p) srow[p] = 0.f;

  f32x4 ldA[8], ldB[8];
#define LOADA(s) { _Pragma("unroll") for (int p = 0; p < 8; ++p) \
    ldA[p] = *(const f32x4*)(xb + (size_t)(p * 16 + rquad) * Nn + (s) * 64 + c4 * 4); }
#define LOADB(s) { _Pragma("unroll") for (int p = 0; p < 8; ++p) \
    ldB[p] = *(const f32x4*)(xb + (size_t)((p + 8) * 16 + rquad) * Nn + (s) * 64 + c4 * 4); }

  LOADA(0); LOADB(0);

  for (int s = 0; s < 8; ++s) {
    char* buf = smem[s & 1];
    __syncthreads();                          // readers of this buffer done
#pragma unroll
    for (int p = 0; p < 8; ++p) {
      f32x4 v = ldA[p];
      srow[p] += (v.x + v.y) + (v.z + v.w);
      int r = p * 16 + rquad;
      ushort4 hv = make_ushort4(f2h(v.x), f2h(v.y), f2h(v.z), f2h(v.w));
      *(ushort4*)(buf + r * 128 + ((((c4 >> 1) + r) & 7) << 4) + (c4 & 1) * 8) = hv;
    }
#pragma unroll
    for (int p = 0; p < 8; ++p) {
      f32x4 v = ldB[p];
      srow[p + 8] += (v.x + v.y) + (v.z + v.w);
      int r = (p + 8) * 16 + rquad;
      ushort4 hv = make_ushort4(f2h(v.x), f2h(v.y), f2h(v.z), f2h(v.w));
      *(ushort4*)(buf + r * 128 + ((((c4 >> 1) + r) & 7) << 4) + (c4 & 1) * 8) = hv;
    }
    __syncthreads();                          // buffer ready
    if (s < 7) { LOADA(s + 1); LOADB(s + 1); }   // in flight across compute
#pragma unroll
    for (int ks = 0; ks < 4; ++ks) {
      const int cp = ks * 2 + kh;             // 16B k-chunk 0..7
      u16x8 A[4], Bv[2];
#pragma unroll
      for (int m = 0; m < 4; ++m) {
        int r = half * 128 + m * 32 + ln;
        A[m] = *(const u16x8*)(buf + r * 128 + (((cp + r) & 7) << 4));
      }
#pragma unroll
      for (int n = 0; n < 2; ++n) {
        int r = w * 64 + n * 32 + ln;
        Bv[n] = *(const u16x8*)(buf + r * 128 + (((cp + r) & 7) << 4));
      }
#pragma unroll
      for (int m = 0; m < 4; ++m)
#pragma unroll
        for (int n = 0; n < 2; ++n)
          acc[m][n] = mfma16h(A[m], Bv[n], acc[m][n]);
    }
  }
#undef LOADA
#undef LOADB

  if (half == 0) {                            // row sums: one x pass contributes once
#pragma unroll
    for (int p = 0; p < 16; ++p) {
      float v = srow[p];
      v += __shfl_xor(v, 1);
      v += __shfl_xor(v, 2);
      v += __shfl_xor(v, 4);
      v += __shfl_xor(v, 8);
      if (c4 == 0) atomicAdd(&sv[b * Cn + p * 16 + rquad], v);
    }
  }

  float* gb = G + (size_t)b * 65536;
#pragma unroll
  for (int m = 0; m < 4; ++m)
#pragma unroll
    for (int n = 0; n < 2; ++n)
#pragma unroll
      for (int r2 = 0; r2 < 16; ++r2) {
        int row = half * 128 + m * 32 + (r2 & 3) + 8 * (r2 >> 2) + 4 * kh;
        int col = w * 64 + n * 32 + ln;
        atomicAdd(&gb[row * Cn + col], acc[m][n][r2]);
      }
}

// ---------------- K2 (k_misc, 8 blocks): kN = Wk s + N bk ----------------
__global__ __launch_bounds__(256) void k_misc(
    const float* __restrict__ sv, const float* __restrict__ wk,
    const float* __restrict__ bk, float* __restrict__ kN) {
  const int bb = blockIdx.x, t = threadIdx.x;
  __shared__ float s_l[256];
  s_l[t] = sv[bb * Cn + t];
  __syncthreads();
  float k2 = 0.f;
  for (int c0 = 0; c0 < 256; c0 += 4) {
    f32x4 wv = *(const f32x4*)(&wk[t * Cn + c0]);
    f32x4 sl = *(const f32x4*)(&s_l[c0]);
    k2 += wv.x * sl.x + wv.y * sl.y + wv.z * sl.z + wv.w * sl.w;
  }
  kN[bb * Cn + t] = k2 + 16384.f * bk[t];
}

// ---------------- K3 (k_gk): GK = G @ Wk^T + s*bk^T  (G is L2/L3-resident, 2MB) ----------
__global__ __launch_bounds__(256) void k_gk(
    const float* __restrict__ G, const float* __restrict__ sv,
    const float* __restrict__ wk, const float* __restrict__ bk,
    float* __restrict__ GK) {
  const int b = blockIdx.x >> 6, tile = blockIdx.x & 63;
  const int r0 = tile * 4, t = threadIdx.x;
  __shared__ float g_l[4][256];

#pragma unroll
  for (int j = 0; j < 4; ++j)
    g_l[j][t] = G[(size_t)b * 65536 + (r0 + j) * 256 + t];
  __syncthreads();

  float acc[4] = {0.f, 0.f, 0.f, 0.f};
  for (int k0 = 0; k0 < 256; k0 += 4) {
    f32x4 wv = *(const f32x4*)(&wk[t * Cn + k0]);   // wkT[k0..k0+3][t]
#pragma unroll
    for (int r = 0; r < 4; ++r) {
      f32x4 gv = *(const f32x4*)(&g_l[r][k0]);
      acc[r] += gv.x * wv.x + gv.y * wv.y + gv.z * wv.z + gv.w * wv.w;
    }
  }
  float bkt = bk[t];
#pragma unroll
  for (int r = 0; r < 4; ++r) {
    float svr = sv[b * 256 + r0 + r];
    GK[((size_t)b * 256 + r0 + r) * 256 + t] = acc[r] + svr * bkt;
  }
}

// ---------------- K4 (k_scores): scores = Wq@GK + bq*kN^T; softmax; ccB(+I) fp16 ----------------
__global__ __launch_bounds__(256) void k_scores(
    const float* __restrict__ wq, const float* __restrict__ GK,
    const float* __restrict__ bq, const float* __restrict__ kN,
    unsigned short* __restrict__ ccB) {
  const int b    = blockIdx.x >> 5;
  const int tile = blockIdx.x & 31;
  const int c0   = tile * 8;
  const int t    = threadIdx.x;

  __shared__ float wq_l[8][256];
  __shared__ float sc_l[8][256];
  __shared__ unsigned short cct_l[256][8];

#pragma unroll
  for (int j = 0; j < 8; ++j) wq_l[j][t] = wq[(c0 + j) * Cn + t];
  __syncthreads();

  float acc[8];
#pragma unroll
  for (int r = 0; r < 8; ++r) acc[r] = 0.f;
  for (int k0 = 0; k0 < 256; k0 += 4) {
    float g0 = GK[((size_t)b * 256 + k0 + 0) * 256 + t];
    float g1 = GK[((size_t)b * 256 + k0 + 1) * 256 + t];
    float g2 = GK[((size_t)b * 256 + k0 + 2) * 256 + t];
    float g3 = GK[((size_t)b * 256 + k0 + 3) * 256 + t];
#pragma unroll
    for (int r = 0; r < 8; ++r) {
      f32x4 qv = *(const f32x4*)(&wq_l[r][k0]);
      acc[r] += qv.x * g0 + qv.y * g1 + qv.z * g2 + qv.w * g3;
    }
  }
  float kNt = kN[b * 256 + t];
#pragma unroll
  for (int r = 0; r < 8; ++r) sc_l[r][t] = acc[r] + bq[c0 + r] * kNt;
  __syncthreads();

  const int r = t >> 5, sub = t & 31;
  float v[8];
#pragma unroll
  for (int j = 0; j < 8; ++j) v[j] = sc_l[r][sub + 32 * j];
  float mx = v[0];
#pragma unroll
  for (int j = 1; j < 8; ++j) mx = fmaxf(mx, v[j]);
#pragma unroll
  for (int msk = 16; msk >= 1; msk >>= 1) mx = fmaxf(mx, __shfl_xor(mx, msk, 32));
  float se = 0.f;
#pragma unroll
  for (int j = 0; j < 8; ++j) { v[j] = __expf(v[j] - mx); se += v[j]; }
#pragma unroll
  for (int msk = 16; msk >= 1; msk >>= 1) se += __shfl_xor(se, msk, 32);
  float inv = 1.f / se;
#pragma unroll
  for (int j = 0; j < 8; ++j) {
    int d = sub + 32 * j;
    float cc = v[j] * inv + ((d == c0 + r) ? 1.f : 0.f);   // fold residual: cc + I
    cct_l[d][r] = f2h(cc);
  }
  __syncthreads();
  *(uint4*)(ccB + (size_t)b * 65536 + (size_t)(tile * 256 + t) * 8) =
      *(const uint4*)(&cct_l[t][0]);
}

// ---------------- K5 (k_out): out = x @ (cc + I), direct fp32 x, 128-row blocks ----------
__global__ __launch_bounds__(256, 2) void k_out(
    const float* __restrict__ x, const unsigned short* __restrict__ ccB,
    float* __restrict__ out) {
  const int b  = blockIdx.x & 7;             // 1 batch per XCD
  const int n0 = (blockIdx.x >> 3) << 7;     // 128-row tiles
  const float* xb = x + (size_t)b * ((size_t)Nn * Cn) + (size_t)n0 * Cn;
  const unsigned short* cb = ccB + (size_t)b * 65536;
  float* ob = out + (size_t)b * ((size_t)Nn * Cn) + (size_t)n0 * Cn;

  __shared__ __align__(16) char smem[65536];  // [128 rows][512B] fp16

  const int t    = threadIdx.x;
  const int lane = t & 63;
  const int w    = t >> 6;                   // col group (d = w*64..)
  const int ln = lane & 31;
  const int kh = lane >> 5;

  f32x16 acc[4][2];
#pragma unroll
  for (int m = 0; m < 4; ++m)
#pragma unroll
    for (int n = 0; n < 2; ++n)
#pragma unroll
      for (int i = 0; i < 16; ++i) acc[m][n][i] = 0.f;

#pragma unroll
  for (int q = 0; q < 4; ++q) {
    f32x4 v[8];
#pragma unroll
    for (int i = 0; i < 8; ++i)
      v[i] = *(const f32x4*)(xb + (size_t)((q * 8 + i) * 256 + t) * 4);
#pragma unroll
    for (int i = 0; i < 8; ++i) {
      int fi = (q * 8 + i) * 256 + t;        // f32x4 index: row = fi>>6, c4 = fi&63
      int r = fi >> 6, c4 = fi & 63;
      ushort4 hv = make_ushort4(f2h(v[i].x), f2h(v[i].y), f2h(v[i].z), f2h(v[i].w));
      *(ushort4*)(smem + r * 512 + ((((c4 >> 1) + r) & 31) << 4) + (c4 & 1) * 8) = hv;
    }
  }
  __syncthreads();

#pragma unroll
  for (int ks = 0; ks < 16; ++ks) {
    const int cp = ks * 2 + kh;              // 16B k-chunk 0..31
    u16x8 A[4], Bv[2];
#pragma unroll
    for (int m = 0; m < 4; ++m) {
      int r = m * 32 + ln;
      A[m] = *(const u16x8*)(smem + r * 512 + (((cp + r) & 31) << 4));
    }
#pragma unroll
    for (int n = 0; n < 2; ++n) {
      int d = w * 64 + n * 32 + ln;
      Bv[n] = *(const u16x8*)(cb + (size_t)cp * 2048 + (size_t)d * 8);
    }
#pragma unroll
    for (int m = 0; m < 4; ++m)
#pragma unroll
      for (int n = 0; n < 2; ++n)
        acc[m][n] = mfma16h(A[m], Bv[n], acc[m][n]);
  }

#pragma unroll
  for (int m = 0; m < 4; ++m)
#pragma unroll
    for (int n = 0; n < 2; ++n)
#pragma unroll
      for (int r2 = 0; r2 < 16; ++r2) {
        int row = m * 32 + (r2 & 3) + 8 * (r2 >> 2) + 4 * kh;
        int col = w * 64 + n * 32 + ln;
        ob[(size_t)row * Cn + col] = acc[m][n][r2];
      }
}

extern "C" void kernel_launch(void* const* d_in, const int* in_sizes, int n_in,
                              void* d_out, int out_size, void* d_ws, size_t ws_size,
                              hipStream_t stream) {
  const float* x  = (const float*)d_in[0];
  const float* wq = (const float*)d_in[1];
  const float* bq = (const float*)d_in[2];
  const float* wk = (const float*)d_in[3];
  const float* bk = (const float*)d_in[4];
  float* out = (float*)d_out;

  float* G   = (float*)d_ws;                           // [B][256][256] 2MB (atomic)
  float* sv  = G + (size_t)Bn * 65536;                 // [B][256] (atomic)
  float* kN  = sv + (size_t)Bn * 256;                  // [B][256]
  float* GK  = kN + (size_t)Bn * 256;                  // [B][256][256]
  unsigned short* ccB = (unsigned short*)(GK + (size_t)Bn * 65536); // [B][32][256][8] fp16

  // zero the atomic targets (G + sv) every launch
  hipMemsetAsync(G, 0, ((size_t)Bn * 65536 + (size_t)Bn * 256) * sizeof(float), stream);
  hipLaunchKernelGGL(k_gram,   dim3(Bn * NC * 2), dim3(256), 0, stream, x, G, sv);
  hipLaunchKernelGGL(k_misc,   dim3(Bn),          dim3(256), 0, stream, sv, wk, bk, kN);
  hipLaunchKernelGGL(k_gk,     dim3(Bn * 64),     dim3(256), 0, stream, G, sv, wk, bk, GK);
  hipLaunchKernelGGL(k_scores, dim3(Bn * 32),     dim3(256), 0, stream, wq, GK, bq, kN, ccB);
  hipLaunchKernelGGL(k_out,    dim3(Bn * 128),    dim3(256), 0, stream, x, ccB, out);
}

// Round 12
// 137.651 us; speedup vs baseline: 1.2737x; 1.2737x over previous
//
#include <hip/hip_runtime.h>

#define Bn 8
#define Nn 16384
#define Cn 256
#define NC 32                   // split-K chunks over N (gram); K=512 per ck

typedef __attribute__((ext_vector_type(4)))  float f32x4;
typedef __attribute__((ext_vector_type(16))) float f32x16;
typedef __attribute__((ext_vector_type(8)))  _Float16 f16x8;
typedef __attribute__((ext_vector_type(8)))  unsigned short u16x8;

static __device__ __forceinline__ unsigned short f2h(float f) {
    return __builtin_bit_cast(unsigned short, (_Float16)f);
}
static __device__ __forceinline__ float h2f(unsigned short h) {
    return (float)__builtin_bit_cast(_Float16, h);
}
static __device__ __forceinline__ f32x16 mfma16h(u16x8 a, u16x8 b, f32x16 c) {
    return __builtin_amdgcn_mfma_f32_32x32x16_f16(
        __builtin_bit_cast(f16x8, a), __builtin_bit_cast(f16x8, b), c, 0, 0, 0);
}

// ---------------- K1 (k_gram): G-partial row-half per block, direct from x (R9 structure) ----
// 512 blocks (b=XCD, ck, half); 256 thr = 4 waves (col groups), acc[4][2] (wave 128x64).
// Stage BK=64 cols fp32->fp16 into [256 rows][128B] LDS (rotation swizzle, conflict-free),
// double-buffered; 16 loads/thread in flight across compute. gpart stored as FP16 (32MB).
__global__ __launch_bounds__(256, 2) void k_gram(
    const float* __restrict__ x, unsigned short* __restrict__ gph,
    float* __restrict__ spart) {
  const int b    = blockIdx.x & 7;           // 1 batch per XCD
  const int loc  = blockIdx.x >> 3;          // 0..63; halves adjacent in dispatch
  const int ck   = loc >> 1;
  const int half = loc & 1;

  __shared__ __align__(16) char smem[2][32768];   // [256 rows][128B] fp16

  const int t     = threadIdx.x;
  const int lane  = t & 63;
  const int w     = t >> 6;                  // col group (cols w*64..)
  const int ln    = lane & 31, kh = lane >> 5;
  const int rquad = t >> 4;                  // 0..15
  const int c4    = t & 15;                  // 16B column slot within 64-col stage

  const float* xb = x + (size_t)b * ((size_t)Cn * Nn) + (size_t)ck * 512;

  f32x16 acc[4][2];
#pragma unroll
  for (int m = 0; m < 4; ++m)
#pragma unroll
    for (int n = 0; n < 2; ++n)
#pragma unroll
      for (int i = 0; i < 16; ++i) acc[m][n][i] = 0.f;

  float srow[16];
#pragma unroll
  for (int p = 0; p < 16; ++p) srow[p] = 0.f;

  f32x4 ldA[8], ldB[8];
#define LOADA(s) { _Pragma("unroll") for (int p = 0; p < 8; ++p) \
    ldA[p] = *(const f32x4*)(xb + (size_t)(p * 16 + rquad) * Nn + (s) * 64 + c4 * 4); }
#define LOADB(s) { _Pragma("unroll") for (int p = 0; p < 8; ++p) \
    ldB[p] = *(const f32x4*)(xb + (size_t)((p + 8) * 16 + rquad) * Nn + (s) * 64 + c4 * 4); }

  LOADA(0); LOADB(0);

  for (int s = 0; s < 8; ++s) {
    char* buf = smem[s & 1];
    __syncthreads();                          // readers of this buffer done
#pragma unroll
    for (int p = 0; p < 8; ++p) {
      f32x4 v = ldA[p];
      srow[p] += (v.x + v.y) + (v.z + v.w);
      int r = p * 16 + rquad;
      ushort4 hv = make_ushort4(f2h(v.x), f2h(v.y), f2h(v.z), f2h(v.w));
      *(ushort4*)(buf + r * 128 + ((((c4 >> 1) + r) & 7) << 4) + (c4 & 1) * 8) = hv;
    }
#pragma unroll
    for (int p = 0; p < 8; ++p) {
      f32x4 v = ldB[p];
      srow[p + 8] += (v.x + v.y) + (v.z + v.w);
      int r = (p + 8) * 16 + rquad;
      ushort4 hv = make_ushort4(f2h(v.x), f2h(v.y), f2h(v.z), f2h(v.w));
      *(ushort4*)(buf + r * 128 + ((((c4 >> 1) + r) & 7) << 4) + (c4 & 1) * 8) = hv;
    }
    __syncthreads();                          // buffer ready
    if (s < 7) { LOADA(s + 1); LOADB(s + 1); }   // in flight across compute
#pragma unroll
    for (int ks = 0; ks < 4; ++ks) {
      const int cp = ks * 2 + kh;             // 16B k-chunk 0..7
      u16x8 A[4], Bv[2];
#pragma unroll
      for (int m = 0; m < 4; ++m) {
        int r = half * 128 + m * 32 + ln;
        A[m] = *(const u16x8*)(buf + r * 128 + (((cp + r) & 7) << 4));
      }
#pragma unroll
      for (int n = 0; n < 2; ++n) {
        int r = w * 64 + n * 32 + ln;
        Bv[n] = *(const u16x8*)(buf + r * 128 + (((cp + r) & 7) << 4));
      }
#pragma unroll
      for (int m = 0; m < 4; ++m)
#pragma unroll
        for (int n = 0; n < 2; ++n)
          acc[m][n] = mfma16h(A[m], Bv[n], acc[m][n]);
    }
  }
#undef LOADA
#undef LOADB

  if (half == 0) {                            // row sums (x contributes once per chunk)
#pragma unroll
    for (int p = 0; p < 16; ++p) {
      float v = srow[p];
      v += __shfl_xor(v, 1);
      v += __shfl_xor(v, 2);
      v += __shfl_xor(v, 4);
      v += __shfl_xor(v, 8);
      if (c4 == 0) spart[(size_t)(b * NC + ck) * Cn + p * 16 + rquad] = v;
    }
  }

  unsigned short* gp = gph + (size_t)(b * NC + ck) * (Cn * Cn);
#pragma unroll
  for (int m = 0; m < 4; ++m)
#pragma unroll
    for (int n = 0; n < 2; ++n)
#pragma unroll
      for (int r2 = 0; r2 < 16; ++r2) {
        int row = half * 128 + m * 32 + (r2 & 3) + 8 * (r2 >> 2) + 4 * kh;
        int col = w * 64 + n * 32 + ln;
        gp[row * Cn + col] = f2h(acc[m][n][r2]);
      }
}

// ---------------- K2 (k_misc, 8 blocks): sv = sum spart; kN = Wk s + N bk ----------------
__global__ __launch_bounds__(256) void k_misc(
    const float* __restrict__ spart, const float* __restrict__ wk,
    const float* __restrict__ bk, float* __restrict__ sv,
    float* __restrict__ kN) {
  const int bb = blockIdx.x, t = threadIdx.x;
  __shared__ float s_l[256];
  float a = 0.f;
#pragma unroll
  for (int q = 0; q < NC; ++q) a += spart[(size_t)(bb * NC + q) * Cn + t];
  sv[bb * Cn + t] = a;
  s_l[t] = a;
  __syncthreads();
  float k2 = 0.f;
  for (int c0 = 0; c0 < 256; c0 += 4) {
    f32x4 wv = *(const f32x4*)(&wk[t * Cn + c0]);
    f32x4 sl = *(const f32x4*)(&s_l[c0]);
    k2 += wv.x * sl.x + wv.y * sl.y + wv.z * sl.z + wv.w * sl.w;
  }
  kN[bb * Cn + t] = k2 + 16384.f * bk[t];
}

// ---------------- K3 (k_gk): reduce fp16 gpart (coalesced u16x8) + GK = G@Wk^T + s*bk^T ----
// 256 blocks (b, 8-row tile). Phase 1: thread (j=t>>5, c8=t&31) streams 32 partials of
// its u16x8 slice (16B/lane, fully coalesced), reduces in fp32, stages g_l[8][256].
__global__ __launch_bounds__(256) void k_gk(
    const unsigned short* __restrict__ gph, const float* __restrict__ sv,
    const float* __restrict__ wk, const float* __restrict__ bk,
    float* __restrict__ GK) {
  const int b = blockIdx.x >> 5, tile = blockIdx.x & 31;
  const int r0 = tile * 8, t = threadIdx.x;
  __shared__ float g_l[8][256];

  const int j  = t >> 5;                      // row within tile
  const int c8 = t & 31;                      // u16x8 column group
  float a8[8];
#pragma unroll
  for (int i = 0; i < 8; ++i) a8[i] = 0.f;
  const unsigned short* gp = gph + (size_t)b * NC * 65536 + (r0 + j) * 256 + c8 * 8;
  for (int ck = 0; ck < NC; ++ck) {
    u16x8 v = *(const u16x8*)(gp + (size_t)ck * 65536);
#pragma unroll
    for (int i = 0; i < 8; ++i) a8[i] += h2f(v[i]);
  }
#pragma unroll
  for (int i = 0; i < 8; ++i) g_l[j][c8 * 8 + i] = a8[i];
  __syncthreads();

  float acc[8];
#pragma unroll
  for (int r = 0; r < 8; ++r) acc[r] = 0.f;
  for (int k0 = 0; k0 < 256; k0 += 4) {
    f32x4 wv = *(const f32x4*)(&wk[t * Cn + k0]);   // wkT[k0..k0+3][t]
#pragma unroll
    for (int r = 0; r < 8; ++r) {
      f32x4 gv = *(const f32x4*)(&g_l[r][k0]);
      acc[r] += gv.x * wv.x + gv.y * wv.y + gv.z * wv.z + gv.w * wv.w;
    }
  }
  float bkt = bk[t];
#pragma unroll
  for (int r = 0; r < 8; ++r) {
    float svr = sv[b * 256 + r0 + r];
    GK[((size_t)b * 256 + r0 + r) * 256 + t] = acc[r] + svr * bkt;
  }
}

// ---------------- K4 (k_scores): scores = Wq@GK + bq*kN^T; softmax; ccB(+I) fp16 ----------------
__global__ __launch_bounds__(256) void k_scores(
    const float* __restrict__ wq, const float* __restrict__ GK,
    const float* __restrict__ bq, const float* __restrict__ kN,
    unsigned short* __restrict__ ccB) {
  const int b    = blockIdx.x >> 5;
  const int tile = blockIdx.x & 31;
  const int c0   = tile * 8;
  const int t    = threadIdx.x;

  __shared__ float wq_l[8][256];
  __shared__ float sc_l[8][256];
  __shared__ unsigned short cct_l[256][8];

#pragma unroll
  for (int j = 0; j < 8; ++j) wq_l[j][t] = wq[(c0 + j) * Cn + t];
  __syncthreads();

  float acc[8];
#pragma unroll
  for (int r = 0; r < 8; ++r) acc[r] = 0.f;
  for (int k0 = 0; k0 < 256; k0 += 4) {
    float g0 = GK[((size_t)b * 256 + k0 + 0) * 256 + t];
    float g1 = GK[((size_t)b * 256 + k0 + 1) * 256 + t];
    float g2 = GK[((size_t)b * 256 + k0 + 2) * 256 + t];
    float g3 = GK[((size_t)b * 256 + k0 + 3) * 256 + t];
#pragma unroll
    for (int r = 0; r < 8; ++r) {
      f32x4 qv = *(const f32x4*)(&wq_l[r][k0]);
      acc[r] += qv.x * g0 + qv.y * g1 + qv.z * g2 + qv.w * g3;
    }
  }
  float kNt = kN[b * 256 + t];
#pragma unroll
  for (int r = 0; r < 8; ++r) sc_l[r][t] = acc[r] + bq[c0 + r] * kNt;
  __syncthreads();

  const int r = t >> 5, sub = t & 31;
  float v[8];
#pragma unroll
  for (int j = 0; j < 8; ++j) v[j] = sc_l[r][sub + 32 * j];
  float mx = v[0];
#pragma unroll
  for (int j = 1; j < 8; ++j) mx = fmaxf(mx, v[j]);
#pragma unroll
  for (int msk = 16; msk >= 1; msk >>= 1) mx = fmaxf(mx, __shfl_xor(mx, msk, 32));
  float se = 0.f;
#pragma unroll
  for (int j = 0; j < 8; ++j) { v[j] = __expf(v[j] - mx); se += v[j]; }
#pragma unroll
  for (int msk = 16; msk >= 1; msk >>= 1) se += __shfl_xor(se, msk, 32);
  float inv = 1.f / se;
#pragma unroll
  for (int j = 0; j < 8; ++j) {
    int d = sub + 32 * j;
    float cc = v[j] * inv + ((d == c0 + r) ? 1.f : 0.f);   // fold residual: cc + I
    cct_l[d][r] = f2h(cc);
  }
  __syncthreads();
  *(uint4*)(ccB + (size_t)b * 65536 + (size_t)(tile * 256 + t) * 8) =
      *(const uint4*)(&cct_l[t][0]);
}

// ---------------- K5 (k_out): out = x @ (cc + I), direct fp32 x, 128-row blocks ----------
__global__ __launch_bounds__(256, 2) void k_out(
    const float* __restrict__ x, const unsigned short* __restrict__ ccB,
    float* __restrict__ out) {
  const int b  = blockIdx.x & 7;             // 1 batch per XCD
  const int n0 = (blockIdx.x >> 3) << 7;     // 128-row tiles
  const float* xb = x + (size_t)b * ((size_t)Nn * Cn) + (size_t)n0 * Cn;
  const unsigned short* cb = ccB + (size_t)b * 65536;
  float* ob = out + (size_t)b * ((size_t)Nn * Cn) + (size_t)n0 * Cn;

  __shared__ __align__(16) char smem[65536];  // [128 rows][512B] fp16

  const int t    = threadIdx.x;
  const int lane = t & 63;
  const int w    = t >> 6;                   // col group (d = w*64..)
  const int ln = lane & 31;
  const int kh = lane >> 5;

  f32x16 acc[4][2];
#pragma unroll
  for (int m = 0; m < 4; ++m)
#pragma unroll
    for (int n = 0; n < 2; ++n)
#pragma unroll
      for (int i = 0; i < 16; ++i) acc[m][n][i] = 0.f;

#pragma unroll
  for (int q = 0; q < 4; ++q) {
    f32x4 v[8];
#pragma unroll
    for (int i = 0; i < 8; ++i)
      v[i] = *(const f32x4*)(xb + (size_t)((q * 8 + i) * 256 + t) * 4);
#pragma unroll
    for (int i = 0; i < 8; ++i) {
      int fi = (q * 8 + i) * 256 + t;        // f32x4 index: row = fi>>6, c4 = fi&63
      int r = fi >> 6, c4 = fi & 63;
      ushort4 hv = make_ushort4(f2h(v[i].x), f2h(v[i].y), f2h(v[i].z), f2h(v[i].w));
      *(ushort4*)(smem + r * 512 + ((((c4 >> 1) + r) & 31) << 4) + (c4 & 1) * 8) = hv;
    }
  }
  __syncthreads();

#pragma unroll
  for (int ks = 0; ks < 16; ++ks) {
    const int cp = ks * 2 + kh;              // 16B k-chunk 0..31
    u16x8 A[4], Bv[2];
#pragma unroll
    for (int m = 0; m < 4; ++m) {
      int r = m * 32 + ln;
      A[m] = *(const u16x8*)(smem + r * 512 + (((cp + r) & 31) << 4));
    }
#pragma unroll
    for (int n = 0; n < 2; ++n) {
      int d = w * 64 + n * 32 + ln;
      Bv[n] = *(const u16x8*)(cb + (size_t)cp * 2048 + (size_t)d * 8);
    }
#pragma unroll
    for (int m = 0; m < 4; ++m)
#pragma unroll
      for (int n = 0; n < 2; ++n)
        acc[m][n] = mfma16h(A[m], Bv[n], acc[m][n]);
  }

#pragma unroll
  for (int m = 0; m < 4; ++m)
#pragma unroll
    for (int n = 0; n < 2; ++n)
#pragma unroll
      for (int r2 = 0; r2 < 16; ++r2) {
        int row = m * 32 + (r2 & 3) + 8 * (r2 >> 2) + 4 * kh;
        int col = w * 64 + n * 32 + ln;
        ob[(size_t)row * Cn + col] = acc[m][n][r2];
      }
}

extern "C" void kernel_launch(void* const* d_in, const int* in_sizes, int n_in,
                              void* d_out, int out_size, void* d_ws, size_t ws_size,
                              hipStream_t stream) {
  const float* x  = (const float*)d_in[0];
  const float* wq = (const float*)d_in[1];
  const float* bq = (const float*)d_in[2];
  const float* wk = (const float*)d_in[3];
  const float* bk = (const float*)d_in[4];
  float* out = (float*)d_out;

  unsigned short* gph = (unsigned short*)d_ws;          // [B][NC][256][256] fp16, 32MB
  float* spart = (float*)(gph + (size_t)Bn * NC * 65536);  // [B][NC][256]
  float* sv    = spart + (size_t)Bn * NC * 256;         // [B][256]
  float* kN    = sv + (size_t)Bn * 256;                 // [B][256]
  float* GK    = kN + (size_t)Bn * 256;                 // [B][256][256]
  unsigned short* ccB = (unsigned short*)(GK + (size_t)Bn * 65536); // [B][32][256][8] fp16

  hipLaunchKernelGGL(k_gram,   dim3(Bn * NC * 2), dim3(256), 0, stream, x, gph, spart);
  hipLaunchKernelGGL(k_misc,   dim3(Bn),          dim3(256), 0, stream, spart, wk, bk, sv, kN);
  hipLaunchKernelGGL(k_gk,     dim3(Bn * 32),     dim3(256), 0, stream, gph, sv, wk, bk, GK);
  hipLaunchKernelGGL(k_scores, dim3(Bn * 32),     dim3(256), 0, stream, wq, GK, bq, kN, ccB);
  hipLaunchKernelGGL(k_out,    dim3(Bn * 128),    dim3(256), 0, stream, x, ccB, out);
}